// Round 1
// baseline (89.791 us; speedup 1.0000x reference)
//
#include <hip/hip_runtime.h>

// CCNN band-sparse rewrite.
// Key identities vs reference:
//  - band mask keeps only j in [i-5, i-1]  (k=5, both filters)
//  - layer4 is linear => sum_j (h3_j@W4 + B4) = (sum_j h3_j)@W4 + n_j*B4
//  - out[b,i] depends only on x[b,i] -> filters chain locally per (b,i)
//
// Kernel 1: H[f][b,i][16] = sum_{valid j} h3(f, s=t_i-t_j)   (heavy MLP, fully parallel)
// Kernel 2: per (b,i): x1 = x0^T (H0@W4+n*B4); x2 = x1^T (H1@W4+n*B4); write x2.

#define KSZ 5

__global__ __launch_bounds__(64) void ccnn_h3_kernel(
    const float* __restrict__ times,   // (4,512)
    const float* __restrict__ W1, const float* __restrict__ B1,   // (2,16) (2,16)
    const float* __restrict__ W2, const float* __restrict__ B2,   // (2,16,32) (2,32)
    const float* __restrict__ W3, const float* __restrict__ B3,   // (2,32,16) (2,16)
    float* __restrict__ H)             // ws: (2, 2048, 16)
{
    __shared__ __align__(16) float sW1[16];
    __shared__ __align__(16) float sB1[16];
    __shared__ __align__(16) float sW2[512];
    __shared__ __align__(16) float sB2[32];
    __shared__ __align__(16) float sW3[512];
    __shared__ __align__(16) float sB3[16];

    const int tid = threadIdx.x;
    const int f   = (blockIdx.x >= 256) ? 1 : 0;   // 256 blocks per filter

    for (int idx = tid; idx < 512; idx += 64) {
        sW2[idx] = W2[f * 512 + idx];
        sW3[idx] = W3[f * 512 + idx];
    }
    if (tid < 16) {
        sW1[tid] = W1[f * 16 + tid];
        sB1[tid] = B1[f * 16 + tid];
        sB3[tid] = B3[f * 16 + tid];
    }
    if (tid < 32) sB2[tid] = B2[f * 32 + tid];
    __syncthreads();

    const int gid = blockIdx.x * 64 + tid;
    const int rem = gid & 16383;       // 2048*8 per filter
    const int bi  = rem >> 3;          // 0..2047
    const int jo  = rem & 7;           // j-offset slot (0..7; only 0..4 valid)
    const int i   = bi & 511;
    const int b   = bi >> 9;
    const int j   = i - 1 - jo;
    const bool valid = (jo < KSZ) && (j >= 0);

    float s = 0.0f;
    if (valid) {
        float ti = times[b * 512 + i];
        float tj = times[b * 512 + j];
        s = fmaxf(ti - tj, 0.0f);
    }

    // layer 1: 1 -> 16
    float h1[16];
    #pragma unroll
    for (int o = 0; o < 16; ++o)
        h1[o] = fmaxf(fmaf(s, sW1[o], sB1[o]), 0.0f);

    // layer 2: 16 -> 32   (LDS broadcast reads, float4)
    float h2[32];
    #pragma unroll
    for (int o4 = 0; o4 < 8; ++o4) {
        float4 a = *(const float4*)&sB2[o4 * 4];
        #pragma unroll
        for (int ii = 0; ii < 16; ++ii) {
            const float4 w = *(const float4*)&sW2[ii * 32 + o4 * 4];
            a.x = fmaf(h1[ii], w.x, a.x);
            a.y = fmaf(h1[ii], w.y, a.y);
            a.z = fmaf(h1[ii], w.z, a.z);
            a.w = fmaf(h1[ii], w.w, a.w);
        }
        h2[o4 * 4 + 0] = fmaxf(a.x, 0.0f);
        h2[o4 * 4 + 1] = fmaxf(a.y, 0.0f);
        h2[o4 * 4 + 2] = fmaxf(a.z, 0.0f);
        h2[o4 * 4 + 3] = fmaxf(a.w, 0.0f);
    }

    // layer 3: 32 -> 16
    float h3[16];
    #pragma unroll
    for (int o4 = 0; o4 < 4; ++o4) {
        float4 a = *(const float4*)&sB3[o4 * 4];
        #pragma unroll
        for (int ii = 0; ii < 32; ++ii) {
            const float4 w = *(const float4*)&sW3[ii * 16 + o4 * 4];
            a.x = fmaf(h2[ii], w.x, a.x);
            a.y = fmaf(h2[ii], w.y, a.y);
            a.z = fmaf(h2[ii], w.z, a.z);
            a.w = fmaf(h2[ii], w.w, a.w);
        }
        h3[o4 * 4 + 0] = fmaxf(a.x, 0.0f);
        h3[o4 * 4 + 1] = fmaxf(a.y, 0.0f);
        h3[o4 * 4 + 2] = fmaxf(a.z, 0.0f);
        h3[o4 * 4 + 3] = fmaxf(a.w, 0.0f);
    }

    // mask invalid j (band mask), then butterfly-sum over the 8 jo slots
    #pragma unroll
    for (int o = 0; o < 16; ++o)
        if (!valid) h3[o] = 0.0f;

    #pragma unroll
    for (int m = 1; m <= 4; m <<= 1) {
        #pragma unroll
        for (int o = 0; o < 16; ++o)
            h3[o] += __shfl_xor(h3[o], m, 64);
    }

    if (jo == 0) {
        float4* dst = (float4*)&H[(f * 2048 + bi) * 16];
        dst[0] = make_float4(h3[0],  h3[1],  h3[2],  h3[3]);
        dst[1] = make_float4(h3[4],  h3[5],  h3[6],  h3[7]);
        dst[2] = make_float4(h3[8],  h3[9],  h3[10], h3[11]);
        dst[3] = make_float4(h3[12], h3[13], h3[14], h3[15]);
    }
}

__global__ __launch_bounds__(256) void ccnn_out_kernel(
    const int*   __restrict__ features,  // (4,512)
    const float* __restrict__ emb,       // (100,8)
    const float* __restrict__ W4,        // (2,16,64)
    const float* __restrict__ B4,        // (2,64)
    const float* __restrict__ H,         // ws: (2,2048,16)
    float* __restrict__ out)             // (4,512,8)
{
    const int lane = threadIdx.x & 63;
    const int w    = threadIdx.x >> 6;
    const int bi   = blockIdx.x * 4 + w;      // one wave per (b,i)
    const int i    = bi & 511;
    const int c    = lane >> 3;               // lane = c*8 + d
    const float n  = (float)min(i, KSZ);      // # valid j in the band

    const int feat = features[bi];
    float x = emb[feat * 8 + c];              // lane holds x[c]

    float xr = 0.0f;
    #pragma unroll
    for (int f = 0; f < 2; ++f) {
        const float* Hp = &H[(f * 2048 + bi) * 16];
        // M[c,d] for o = lane = c*8+d
        float m = n * B4[f * 64 + lane];
        #pragma unroll
        for (int ii = 0; ii < 16; ++ii)
            m = fmaf(Hp[ii], W4[f * 1024 + ii * 64 + lane], m);
        // x'[d] = sum_c x[c] * M[c,d]
        float p = x * m;
        p += __shfl_xor(p, 8, 64);
        p += __shfl_xor(p, 16, 64);
        p += __shfl_xor(p, 32, 64);
        xr = p;                               // every lane: x'[its d]
        // re-broadcast: lane needs x'[its c] for the next filter
        x = __shfl(xr, lane >> 3, 64);
    }

    if (lane < 8) out[bi * 8 + lane] = xr;    // lanes 0..7: d = lane
}

extern "C" void kernel_launch(void* const* d_in, const int* in_sizes, int n_in,
                              void* d_out, int out_size, void* d_ws, size_t ws_size,
                              hipStream_t stream) {
    const float* times    = (const float*)d_in[0];
    const int*   features = (const int*)  d_in[1];
    const float* emb      = (const float*)d_in[2];
    const float* W1       = (const float*)d_in[3];
    const float* B1       = (const float*)d_in[4];
    const float* W2       = (const float*)d_in[5];
    const float* B2       = (const float*)d_in[6];
    const float* W3       = (const float*)d_in[7];
    const float* B3       = (const float*)d_in[8];
    const float* W4       = (const float*)d_in[9];
    const float* B4       = (const float*)d_in[10];
    float* out = (float*)d_out;
    float* H   = (float*)d_ws;   // 2*2048*16 f32 = 256 KiB

    ccnn_h3_kernel<<<512, 64, 0, stream>>>(times, W1, B1, W2, B2, W3, B3, H);
    ccnn_out_kernel<<<512, 256, 0, stream>>>(features, emb, W4, B4, H, out);
}

// Round 2
// 89.365 us; speedup vs baseline: 1.0048x; 1.0048x over previous
//
#include <hip/hip_runtime.h>

// CCNN fully-fused single-kernel version.
// Identities vs reference:
//  - band mask keeps only j in [i-5, i-1] (k=5, both filters)
//  - layer4 linear => sum_j (h3_j@W4 + B4) = (sum_j h3_j)@W4 + n*B4, n = min(i,5)
//  - out[b,i] depends only on x[b,i] -> the 2-filter chain is local per (b,i)
// => one kernel, H kept in LDS, zero workspace, single launch.
//
// Grid: 256 blocks x 128 threads (2 waves).
//   wave = filter f; lane = (bi_local<<3) | jo.
//   Phase 1: per-thread 4-layer MLP on s = relu(t_i - t_{i-1-jo}); butterfly-sum
//            over jo; deposit H[f][bi_local][16] in LDS.
//   Phase 2: per wave, 4 bi chains: x' = x^T (H_f @ W4 + n*B4), f=0 then f=1.

#define KSZ 5

__global__ __launch_bounds__(128) void ccnn_fused_kernel(
    const float* __restrict__ times,     // (4,512)
    const int*   __restrict__ features,  // (4,512)
    const float* __restrict__ emb,       // (100,8)
    const float* __restrict__ W1, const float* __restrict__ B1,  // (2,1,16)(2,16)
    const float* __restrict__ W2, const float* __restrict__ B2,  // (2,16,32)(2,32)
    const float* __restrict__ W3, const float* __restrict__ B3,  // (2,32,16)(2,16)
    const float* __restrict__ W4, const float* __restrict__ B4,  // (2,16,64)(2,64)
    float* __restrict__ out)             // (4,512,8)
{
    __shared__ __align__(16) float sW1[2][16];
    __shared__ __align__(16) float sB1[2][16];
    __shared__ __align__(16) float sW2[2][512];
    __shared__ __align__(16) float sB2[2][32];
    __shared__ __align__(16) float sW3[2][512];
    __shared__ __align__(16) float sB3[2][16];
    __shared__ __align__(16) float sW4[2][1024];
    __shared__ __align__(16) float sB4[2][64];
    __shared__ __align__(16) float sH[2][8][16];

    const int tid = threadIdx.x;

    // ---- stage all weights (layouts are flat-contiguous matches) ----
    for (int idx = tid; idx < 1024; idx += 128) {
        (&sW2[0][0])[idx] = W2[idx];
        (&sW3[0][0])[idx] = W3[idx];
    }
    for (int idx = tid; idx < 2048; idx += 128)
        (&sW4[0][0])[idx] = W4[idx];
    if (tid < 32) {
        (&sW1[0][0])[tid] = W1[tid];
        (&sB1[0][0])[tid] = B1[tid];
        (&sB3[0][0])[tid] = B3[tid];
    }
    if (tid < 64)  (&sB2[0][0])[tid] = B2[tid];
    (&sB4[0][0])[tid & 127] = B4[tid & 127];   // 128 threads -> 128 elems
    __syncthreads();

    const int f    = tid >> 6;          // wave = filter
    const int lane = tid & 63;
    const int bil  = lane >> 3;         // 8 (b,i) pairs per block
    const int jo   = lane & 7;          // j-offset slot (0..4 valid)
    const int bi   = blockIdx.x * 8 + bil;
    const int i    = bi & 511;
    const int b    = bi >> 9;
    const int j    = i - 1 - jo;
    const bool valid = (jo < KSZ) && (j >= 0);

    float s = 0.0f;
    if (valid)
        s = fmaxf(times[b * 512 + i] - times[b * 512 + j], 0.0f);

    // ---- layer 1: 1 -> 16 ----
    float h1[16];
    #pragma unroll
    for (int o = 0; o < 16; ++o)
        h1[o] = fmaxf(fmaf(s, sW1[f][o], sB1[f][o]), 0.0f);

    // ---- layer 2: 16 -> 32 (LDS broadcast, float4) ----
    float h2[32];
    #pragma unroll
    for (int o4 = 0; o4 < 8; ++o4) {
        float4 a = *(const float4*)&sB2[f][o4 * 4];
        #pragma unroll
        for (int ii = 0; ii < 16; ++ii) {
            const float4 w = *(const float4*)&sW2[f][ii * 32 + o4 * 4];
            a.x = fmaf(h1[ii], w.x, a.x);
            a.y = fmaf(h1[ii], w.y, a.y);
            a.z = fmaf(h1[ii], w.z, a.z);
            a.w = fmaf(h1[ii], w.w, a.w);
        }
        h2[o4 * 4 + 0] = fmaxf(a.x, 0.0f);
        h2[o4 * 4 + 1] = fmaxf(a.y, 0.0f);
        h2[o4 * 4 + 2] = fmaxf(a.z, 0.0f);
        h2[o4 * 4 + 3] = fmaxf(a.w, 0.0f);
    }

    // ---- layer 3: 32 -> 16 ----
    float h3[16];
    #pragma unroll
    for (int o4 = 0; o4 < 4; ++o4) {
        float4 a = *(const float4*)&sB3[f][o4 * 4];
        #pragma unroll
        for (int ii = 0; ii < 32; ++ii) {
            const float4 w = *(const float4*)&sW3[f][ii * 16 + o4 * 4];
            a.x = fmaf(h2[ii], w.x, a.x);
            a.y = fmaf(h2[ii], w.y, a.y);
            a.z = fmaf(h2[ii], w.z, a.z);
            a.w = fmaf(h2[ii], w.w, a.w);
        }
        h3[o4 * 4 + 0] = fmaxf(a.x, 0.0f);
        h3[o4 * 4 + 1] = fmaxf(a.y, 0.0f);
        h3[o4 * 4 + 2] = fmaxf(a.z, 0.0f);
        h3[o4 * 4 + 3] = fmaxf(a.w, 0.0f);
    }

    // band mask, then butterfly-sum over the 8 jo slots (xor 1,2,4)
    #pragma unroll
    for (int o = 0; o < 16; ++o)
        if (!valid) h3[o] = 0.0f;
    #pragma unroll
    for (int m = 1; m <= 4; m <<= 1) {
        #pragma unroll
        for (int o = 0; o < 16; ++o)
            h3[o] += __shfl_xor(h3[o], m, 64);
    }

    if (jo == 0) {
        float4* dst = (float4*)&sH[f][bil][0];
        dst[0] = make_float4(h3[0],  h3[1],  h3[2],  h3[3]);
        dst[1] = make_float4(h3[4],  h3[5],  h3[6],  h3[7]);
        dst[2] = make_float4(h3[8],  h3[9],  h3[10], h3[11]);
        dst[3] = make_float4(h3[12], h3[13], h3[14], h3[15]);
    }
    __syncthreads();

    // ---- epilogue: wave w chains bi_local in {4w..4w+3} ----
    const int c = lane >> 3;            // lane = c*8 + d
    #pragma unroll
    for (int q = 0; q < 4; ++q) {
        const int bil2 = f * 4 + q;
        const int bi2  = blockIdx.x * 8 + bil2;
        const int i2   = bi2 & 511;
        const float n  = (float)min(i2, KSZ);

        const int feat = features[bi2];
        float x  = emb[feat * 8 + c];
        float xr = 0.0f;
        #pragma unroll
        for (int ff = 0; ff < 2; ++ff) {
            float m = n * sB4[ff][lane];
            #pragma unroll
            for (int ii = 0; ii < 16; ++ii)
                m = fmaf(sH[ff][bil2][ii], sW4[ff][ii * 64 + lane], m);
            float p = x * m;
            p += __shfl_xor(p, 8, 64);
            p += __shfl_xor(p, 16, 64);
            p += __shfl_xor(p, 32, 64);
            xr = p;                     // xr = x'[d] on every lane
            x  = __shfl(xr, lane >> 3, 64);  // lane needs x'[its c]
        }
        if (lane < 8) out[bi2 * 8 + lane] = xr;
    }
}

extern "C" void kernel_launch(void* const* d_in, const int* in_sizes, int n_in,
                              void* d_out, int out_size, void* d_ws, size_t ws_size,
                              hipStream_t stream) {
    const float* times    = (const float*)d_in[0];
    const int*   features = (const int*)  d_in[1];
    const float* emb      = (const float*)d_in[2];
    const float* W1       = (const float*)d_in[3];
    const float* B1       = (const float*)d_in[4];
    const float* W2       = (const float*)d_in[5];
    const float* B2       = (const float*)d_in[6];
    const float* W3       = (const float*)d_in[7];
    const float* B3       = (const float*)d_in[8];
    const float* W4       = (const float*)d_in[9];
    const float* B4       = (const float*)d_in[10];
    float* out = (float*)d_out;

    ccnn_fused_kernel<<<256, 128, 0, stream>>>(
        times, features, emb, W1, B1, W2, B2, W3, B3, W4, B4, out);
}